// Round 7
// baseline (260.709 us; speedup 1.0000x reference)
//
#include <hip/hip_runtime.h>
#include <hip/hip_bf16.h>
#include <math.h>

// Problem: B=16, C=512, N=H*W=4096, K=32
#define BB 16
#define CC 512
#define NN 4096
#define KK 32

typedef __attribute__((ext_vector_type(8))) short short8;
typedef __attribute__((ext_vector_type(4))) short short4v;
typedef __attribute__((ext_vector_type(4))) float float4v;

static __device__ __forceinline__ unsigned short f2bf(float f) {
  unsigned u = __float_as_uint(f);
  u += 0x7FFF + ((u >> 16) & 1);  // RNE
  return (unsigned short)(u >> 16);
}

static __device__ __forceinline__ short8 cat8(short4v a, short4v b) {
  short8 r;
  r[0] = a[0]; r[1] = a[1]; r[2] = a[2]; r[3] = a[3];
  r[4] = b[0]; r[5] = b[1]; r[6] = b[2]; r[7] = b[3];
  return r;
}

// ws layout (bytes):
//   [0,128)        c2     (32 fp32)
//   [128,32896)    cwP    (32 k x 512 c) bf16, c-PERMUTED within 32-blocks
//   [32896,34944)  asum   (B*K fp32)
//   [35072,+1MB)   accum  (16 b x 32 k x 512 c fp32) — atomic split-K acc
//
// v8: the entire partials round-trip (67MB write + 64MB read + 8MB+8MB
// part2) is bookkeeping — r6 showed the two-stage reduce is not faster
// than single-stage, and fused is pinned at ~80us regardless of staging
// (r5), occupancy (r1/r2), L3 policy (r3), reg pipelining (r4). Replace
// with canonical split-K: fused atomicAdds its [32][512] tile into a 1MB
// out-shaped accumulator (device-scope fp32 atomics, L2/MALL-resident;
// 64-way contention per line max). prep zeroes accum; finalize applies
// out = accum - asum*cw. 3 launches instead of 4, ~147MB less traffic.

// ---------------- K0: prep (+ accum zero) ----------------
__global__ __launch_bounds__(256) void prep_kernel(
    const float* __restrict__ cw, unsigned short* __restrict__ cwP,
    float* __restrict__ c2, float* __restrict__ asum,
    float* __restrict__ accum) {
  int gid = blockIdx.x * 256 + threadIdx.x;  // 16384 threads = K*C
  if (gid < BB * KK) asum[gid] = 0.f;
  // zero the 262144-float accumulator: 16 floats per thread
  {
    float4v z = {0.f, 0.f, 0.f, 0.f};
    float4v* a4 = (float4v*)accum + (size_t)gid * 4;
#pragma unroll
    for (int i = 0; i < 4; ++i) a4[i] = z;
  }
  {
    int k = gid >> 9;
    int cc = gid & 511;
    int cs = cc & ~31;
    int w5 = cc & 31;
    int q = w5 >> 3, j = w5 & 7;
    int src_c = cs + 2 * q + (j & 1) + ((j >> 1) << 3);
    cwP[gid] = f2bf(cw[k * CC + src_c]);
  }
  __shared__ float c2p[KK][8];
  if (blockIdx.x == 0) {
    int k = threadIdx.x >> 3, j = threadIdx.x & 7;
    const float* row = cw + k * CC + j * 64;
    float s = 0.f;
    for (int i = 0; i < 64; ++i) s = fmaf(row[i], row[i], s);
    c2p[k][j] = s;
    __syncthreads();
    if (threadIdx.x < KK) {
      float t = 0.f;
      for (int j2 = 0; j2 < 8; ++j2) t += c2p[threadIdx.x][j2];
      c2[threadIdx.x] = t;
    }
  }
}

// ---------------- K1: fused (r2-exact body, atomic epilogue) ----------
// grid 1024 = 16 b x 64 chunks(64 n); 2 subs of 32 n; 4 blocks/CU.
#define XP2 36
__global__ __launch_bounds__(256, 4) void fused_kernel(
    const float* __restrict__ x, const unsigned short* __restrict__ cwP,
    const float* __restrict__ c2g, const float* __restrict__ scale,
    float* __restrict__ accum, float* __restrict__ asum) {
  const int b = blockIdx.x >> 6;
  const int chunk = blockIdx.x & 63;
  const int t = threadIdx.x;
  const int w = t >> 6;
  const int l = t & 63;
  const int l15 = l & 15;
  const int q = l >> 4;
  const int wrole = (w + (blockIdx.x & 3)) & 3;

  __shared__ unsigned short Xl[CC * XP2];  // 36864 B
  __shared__ unsigned short As[KK * XP2];  // 2304 B
  __shared__ float Sx2w[4 * 32];           // 512 B
  __shared__ float Sx2[32];                // 128 B -> total 39808 B

  const float* xb0 = x + (size_t)b * CC * NN + chunk * 64;
  const float sc0 = scale[l15], sc1 = scale[16 + l15];
  const float cc0 = c2g[l15], cc1 = c2g[16 + l15];

  float4v acc[8][2];
#pragma unroll
  for (int ct = 0; ct < 8; ++ct)
#pragma unroll
    for (int m = 0; m < 2; ++m) acc[ct][m] = (float4v){0.f, 0.f, 0.f, 0.f};
  float s0acc = 0.f, s1acc = 0.f;

  const int f4 = t & 7;   // staging: n = 4*f4 .. 4*f4+3 (32 n per sub)
  const int cr = t >> 3;  // staging: c = cr + 32*i

  for (int sub = 0; sub < 2; ++sub) {
    const float* xb = xb0 + sub * 32;

    // ---- stage x -> Xl bf16; x2 partial per thread (16 c's)
    float4v x2p = (float4v){0.f, 0.f, 0.f, 0.f};
#pragma unroll 8
    for (int i = 0; i < 16; ++i) {
      const int c = cr + 32 * i;
      float4v v = *(const float4v*)(xb + (size_t)c * NN + 4 * f4);
      x2p.x = fmaf(v.x, v.x, x2p.x);
      x2p.y = fmaf(v.y, v.y, x2p.y);
      x2p.z = fmaf(v.z, v.z, x2p.z);
      x2p.w = fmaf(v.w, v.w, x2p.w);
      unsigned p0 = (unsigned)f2bf(v.x) | ((unsigned)f2bf(v.y) << 16);
      unsigned p1 = (unsigned)f2bf(v.z) | ((unsigned)f2bf(v.w) << 16);
      *(uint2*)&Xl[c * XP2 + 4 * f4] = make_uint2(p0, p1);
    }
    // in-wave reduce over the wave's 8 c-rows (lane bits 3,4,5)
#pragma unroll
    for (int m = 8; m <= 32; m <<= 1) {
      x2p.x += __shfl_xor(x2p.x, m);
      x2p.y += __shfl_xor(x2p.y, m);
      x2p.z += __shfl_xor(x2p.z, m);
      x2p.w += __shfl_xor(x2p.w, m);
    }
    if (l < 8) *(float4v*)&Sx2w[w * 32 + 4 * l] = x2p;
    __syncthreads();  // Xl + Sx2w visible

    // ---- phase 1 (waves wrole 0,1): xc via MFMA with permuted c-gather;
    //      wave wrole 2: finish x2 cross-wave sum
    float4v p0 = (float4v){0.f, 0.f, 0.f, 0.f};
    float4v p1 = (float4v){0.f, 0.f, 0.f, 0.f};
    if (wrole < 2) {
      const int nrow = wrole * 16 + l15;
      for (int cs = 0; cs < 512; cs += 32) {
        const int cb2 = cs + 2 * q;
        short8 af;
#pragma unroll
        for (int j = 0; j < 8; ++j) {
          const int c = cb2 + (j & 1) + ((j >> 1) << 3);
          af[j] = (short)Xl[c * XP2 + nrow];
        }
        short8 b0 = *(const short8*)(cwP + (size_t)l15 * CC + cs + q * 8);
        short8 b1 = *(const short8*)(cwP + (size_t)(16 + l15) * CC + cs + q * 8);
        p0 = __builtin_amdgcn_mfma_f32_16x16x32_bf16(af, b0, p0, 0, 0, 0);
        p1 = __builtin_amdgcn_mfma_f32_16x16x32_bf16(af, b1, p1, 0, 0, 0);
      }
    } else if (wrole == 2 && l < 32) {
      Sx2[l] = Sx2w[l] + Sx2w[32 + l] + Sx2w[64 + l] + Sx2w[96 + l];
    }
    __syncthreads();  // Sx2 ready

    // ---- softmax per n (waves wrole 0,1): k spread over l15 lanes
    if (wrole < 2) {
      float a0[4], a1[4];
#pragma unroll
      for (int r = 0; r < 4; ++r) {
        const float xx = Sx2[wrole * 16 + 4 * q + r];
        float l0 = sc0 * (xx - 2.f * p0[r] + cc0);
        float l1 = sc1 * (xx - 2.f * p1[r] + cc1);
        float m = fmaxf(l0, l1);
        m = fmaxf(m, __shfl_xor(m, 1));
        m = fmaxf(m, __shfl_xor(m, 2));
        m = fmaxf(m, __shfl_xor(m, 4));
        m = fmaxf(m, __shfl_xor(m, 8));
        float e0 = __expf(l0 - m), e1 = __expf(l1 - m);
        float s = e0 + e1;
        s += __shfl_xor(s, 1);
        s += __shfl_xor(s, 2);
        s += __shfl_xor(s, 4);
        s += __shfl_xor(s, 8);
        float inv = 1.0f / s;
        a0[r] = e0 * inv;
        a1[r] = e1 * inv;
      }
      s0acc += a0[0] + a0[1] + a0[2] + a0[3];
      s1acc += a1[0] + a1[1] + a1[2] + a1[3];
      unsigned p00 = (unsigned)f2bf(a0[0]) | ((unsigned)f2bf(a0[1]) << 16);
      unsigned p01 = (unsigned)f2bf(a0[2]) | ((unsigned)f2bf(a0[3]) << 16);
      unsigned p10 = (unsigned)f2bf(a1[0]) | ((unsigned)f2bf(a1[1]) << 16);
      unsigned p11 = (unsigned)f2bf(a1[2]) | ((unsigned)f2bf(a1[3]) << 16);
      const int nc = wrole * 16 + 4 * q;
      *(uint2*)&As[l15 * XP2 + nc] = make_uint2(p00, p01);
      *(uint2*)&As[(16 + l15) * XP2 + nc] = make_uint2(p10, p11);
    }
    __syncthreads();  // As ready

    // ---- phase 2 (all waves): out_tile[k][c] += A . x^T over 32 n
    {
      const int nb = q * 8;
      const short4v* Ap0 = (const short4v*)&As[l15 * XP2 + nb];
      const short4v* Ap1 = (const short4v*)&As[(16 + l15) * XP2 + nb];
      short8 am0 = cat8(Ap0[0], Ap0[1]);
      short8 am1 = cat8(Ap1[0], Ap1[1]);
#pragma unroll
      for (int ct = 0; ct < 8; ++ct) {
        const int c = w * 128 + ct * 16 + l15;
        const short4v* Bp = (const short4v*)&Xl[c * XP2 + nb];
        short8 bx = cat8(Bp[0], Bp[1]);
        acc[ct][0] = __builtin_amdgcn_mfma_f32_16x16x32_bf16(am0, bx, acc[ct][0], 0, 0, 0);
        acc[ct][1] = __builtin_amdgcn_mfma_f32_16x16x32_bf16(am1, bx, acc[ct][1], 0, 0, 0);
      }
    }
    __syncthreads();  // protect Xl/As before next sub's staging
  }

  // ---- epilogue: split-K atomic accumulate into out-shaped accum
  float* aout = accum + (size_t)b * KK * CC;
#pragma unroll
  for (int ct = 0; ct < 8; ++ct) {
    const int c = w * 128 + ct * 16 + l15;
#pragma unroll
    for (int m = 0; m < 2; ++m)
#pragma unroll
      for (int r = 0; r < 4; ++r) {
        int k = 16 * m + 4 * q + r;
        atomicAdd(&aout[k * CC + c], acc[ct][m][r]);
      }
  }
  // asum: only the phase-1 waves hold A-sums; reduce over q lanes
  s0acc += __shfl_xor(s0acc, 16);
  s0acc += __shfl_xor(s0acc, 32);
  s1acc += __shfl_xor(s1acc, 16);
  s1acc += __shfl_xor(s1acc, 32);
  if (wrole < 2 && q == 0) {
    atomicAdd(&asum[b * KK + l15], s0acc);
    atomicAdd(&asum[b * KK + 16 + l15], s1acc);
  }
}

// ---------------- K2: finalize — out = accum - asum * cw ----------------
__global__ __launch_bounds__(256) void finalize_kernel(
    const float* __restrict__ accum, const float* __restrict__ asum,
    const float* __restrict__ cw, float* __restrict__ out) {
  int o = blockIdx.x * 256 + threadIdx.x;  // float4 index, 65536 total
  int b = o >> 12;
  int k = (o >> 7) & 31;
  int c4 = o & 127;

  float4v s = ((const float4v*)accum)[o];
  float4v wv = ((const float4v*)cw)[k * 128 + c4];
  float a = asum[b * KK + k];
  s.x -= a * wv.x;
  s.y -= a * wv.y;
  s.z -= a * wv.z;
  s.w -= a * wv.w;
  ((float4v*)out)[o] = s;
}

extern "C" void kernel_launch(void* const* d_in, const int* in_sizes, int n_in,
                              void* d_out, int out_size, void* d_ws, size_t ws_size,
                              hipStream_t stream) {
  const float* x = (const float*)d_in[0];      // (16,512,64,64)
  const float* cw = (const float*)d_in[1];     // (32,512)
  const float* scale = (const float*)d_in[2];  // (32,)
  float* out = (float*)d_out;                  // (16,32,512)
  char* ws = (char*)d_ws;

  float* c2 = (float*)ws;                             // 128 B
  unsigned short* cwP = (unsigned short*)(ws + 128);  // 32 KB
  float* asum = (float*)(ws + 32896);                 // 2 KB
  float* accum = (float*)(ws + 35072);                // 1 MB

  prep_kernel<<<64, 256, 0, stream>>>(cw, cwP, c2, asum, accum);
  fused_kernel<<<1024, 256, 0, stream>>>(x, cwP, c2, scale, accum, asum);
  finalize_kernel<<<256, 256, 0, stream>>>(accum, asum, cw, out);
}

// Round 8
// 226.716 us; speedup vs baseline: 1.1499x; 1.1499x over previous
//
#include <hip/hip_runtime.h>
#include <hip/hip_bf16.h>
#include <math.h>

// Problem: B=16, C=512, N=H*W=4096, K=32
#define BB 16
#define CC 512
#define NN 4096
#define KK 32

typedef __attribute__((ext_vector_type(8))) short short8;
typedef __attribute__((ext_vector_type(4))) short short4v;
typedef __attribute__((ext_vector_type(4))) float float4v;

static __device__ __forceinline__ unsigned short f2bf(float f) {
  unsigned u = __float_as_uint(f);
  u += 0x7FFF + ((u >> 16) & 1);  // RNE
  return (unsigned short)(u >> 16);
}

static __device__ __forceinline__ short8 cat8(short4v a, short4v b) {
  short8 r;
  r[0] = a[0]; r[1] = a[1]; r[2] = a[2]; r[3] = a[3];
  r[4] = b[0]; r[5] = b[1]; r[6] = b[2]; r[7] = b[3];
  return r;
}

// ws layout (bytes):
//   [0,128)        c2     (32 fp32)
//   [128,32896)    cwB    (32 k x 512 c) bf16 PLAIN (permutation removed)
//   [32896,34944)  asum   (B*K fp32)
//   [35072,...)    partials: NBLK x (32 k x 512 c) fp32 (64 MB at NBLK=1024)
//
// v9: budget model (fits r0-r7 within 5us): total = ~138us fixed harness
// (512MB poison fill ~80 + restore/gaps ~58) + prep 3 + fused + reduce ~7.
// Only fused (~82us) is controllable. r5 exonerated staging; the one
// never-restructured serial phase is p1's A-fragment gather: 8 scalar
// ds_read_u16 x 16 iters x 2 waves (transpose read). Fix: stage X in BOTH
// layouts — Xl_c[512][36] for p2 (unchanged) + n-major Xl_n[32][520] so
// p1's fragment is ONE ds_read_b128 (conflict-free: pitch 1040B -> bank
// group 4*(l15+q) mod 32, uniform). cw operand becomes plain bf16 (the
// c-permutation existed only for the scalar gather). LDS 73KB -> 2
// blocks/CU; r0 proved 8 waves ~= 16 waves here, so occupancy is free.

// ---------------- K0: prep ----------------
__global__ __launch_bounds__(256) void prep_kernel(
    const float* __restrict__ cw, unsigned short* __restrict__ cwB,
    float* __restrict__ c2, float* __restrict__ asum) {
  int gid = blockIdx.x * 256 + threadIdx.x;  // 16384 threads = K*C
  if (gid < BB * KK) asum[gid] = 0.f;
  cwB[gid] = f2bf(cw[gid]);  // plain bf16 codewords
  __shared__ float c2p[KK][8];
  if (blockIdx.x == 0) {
    int k = threadIdx.x >> 3, j = threadIdx.x & 7;
    const float* row = cw + k * CC + j * 64;
    float s = 0.f;
    for (int i = 0; i < 64; ++i) s = fmaf(row[i], row[i], s);
    c2p[k][j] = s;
    __syncthreads();
    if (threadIdx.x < KK) {
      float t = 0.f;
      for (int j2 = 0; j2 < 8; ++j2) t += c2p[threadIdx.x][j2];
      c2[threadIdx.x] = t;
    }
  }
}

// ---------------- K1: fused v9 ----------------
//   LOG2CH=6: grid 1024, 64 n/chunk (2 subs); LOG2CH=5: grid 512 (4 subs)
#define XP2 36   // c-major pitch (n-elems) for Xl_c / As
#define XPN 520  // n-major pitch (c-elems): 1040 B rows, b128-conflict-free
template <int LOG2CH>
__global__ __launch_bounds__(256, 2) void fused_kernel(
    const float* __restrict__ x, const unsigned short* __restrict__ cwB,
    const float* __restrict__ c2g, const float* __restrict__ scale,
    float* __restrict__ partials, float* __restrict__ asum) {
  constexpr int CHN = NN >> LOG2CH;  // n per chunk (64 or 128)
  constexpr int SUBS = CHN / 32;     // subs of 32 n (2 or 4)
  const int b = blockIdx.x >> LOG2CH;
  const int chunk = blockIdx.x & ((1 << LOG2CH) - 1);
  const int t = threadIdx.x;
  const int w = t >> 6;
  const int l = t & 63;
  const int l15 = l & 15;
  const int q = l >> 4;
  const int wrole = (w + (blockIdx.x & 3)) & 3;

  __shared__ unsigned short Xl[CC * XP2];   // 36864 B  (c-major, for p2)
  __shared__ unsigned short Xn[32 * XPN];   // 33280 B  (n-major, for p1)
  __shared__ unsigned short As[KK * XP2];   // 2304 B
  __shared__ float Sx2w[4 * 32];            // 512 B
  __shared__ float Sx2[32];                 // 128 B -> total 73088 B

  const float* xb0 = x + (size_t)b * CC * NN + chunk * CHN;
  const float sc0 = scale[l15], sc1 = scale[16 + l15];
  const float cc0 = c2g[l15], cc1 = c2g[16 + l15];

  float4v acc[8][2];
#pragma unroll
  for (int ct = 0; ct < 8; ++ct)
#pragma unroll
    for (int m = 0; m < 2; ++m) acc[ct][m] = (float4v){0.f, 0.f, 0.f, 0.f};
  float s0acc = 0.f, s1acc = 0.f;

  const int f4 = t & 7;   // staging: n = 4*f4 .. 4*f4+3 (32 n per sub)
  const int cr = t >> 3;  // staging: c = cr + 32*i

  for (int sub = 0; sub < SUBS; ++sub) {
    const float* xb = xb0 + sub * 32;

    // ---- stage x -> Xl (c-major) AND Xn (n-major); x2 partial per thread
    float4v x2p = (float4v){0.f, 0.f, 0.f, 0.f};
#pragma unroll 8
    for (int i = 0; i < 16; ++i) {
      const int c = cr + 32 * i;
      float4v v = *(const float4v*)(xb + (size_t)c * NN + 4 * f4);
      x2p.x = fmaf(v.x, v.x, x2p.x);
      x2p.y = fmaf(v.y, v.y, x2p.y);
      x2p.z = fmaf(v.z, v.z, x2p.z);
      x2p.w = fmaf(v.w, v.w, x2p.w);
      unsigned short h0 = f2bf(v.x), h1 = f2bf(v.y);
      unsigned short h2 = f2bf(v.z), h3 = f2bf(v.w);
      *(uint2*)&Xl[c * XP2 + 4 * f4] =
          make_uint2((unsigned)h0 | ((unsigned)h1 << 16),
                     (unsigned)h2 | ((unsigned)h3 << 16));
      Xn[(4 * f4 + 0) * XPN + c] = h0;
      Xn[(4 * f4 + 1) * XPN + c] = h1;
      Xn[(4 * f4 + 2) * XPN + c] = h2;
      Xn[(4 * f4 + 3) * XPN + c] = h3;
    }
    // in-wave reduce over the wave's 8 c-rows (lane bits 3,4,5)
#pragma unroll
    for (int m = 8; m <= 32; m <<= 1) {
      x2p.x += __shfl_xor(x2p.x, m);
      x2p.y += __shfl_xor(x2p.y, m);
      x2p.z += __shfl_xor(x2p.z, m);
      x2p.w += __shfl_xor(x2p.w, m);
    }
    if (l < 8) *(float4v*)&Sx2w[w * 32 + 4 * l] = x2p;
    __syncthreads();  // Xl + Xn + Sx2w visible

    // ---- phase 1 (waves wrole 0,1): xc via MFMA, b128 A-frag from Xn;
    //      wave wrole 2: finish x2 cross-wave sum
    float4v p0 = (float4v){0.f, 0.f, 0.f, 0.f};
    float4v p1 = (float4v){0.f, 0.f, 0.f, 0.f};
    if (wrole < 2) {
      const int nrow = wrole * 16 + l15;
      const unsigned short* xrow = &Xn[nrow * XPN + 8 * q];
      const unsigned short* cw0 = cwB + (size_t)l15 * CC + 8 * q;
      const unsigned short* cw1 = cwB + (size_t)(16 + l15) * CC + 8 * q;
#pragma unroll 4
      for (int cs = 0; cs < 512; cs += 32) {
        short8 af = *(const short8*)(xrow + cs);  // one ds_read_b128
        short8 b0 = *(const short8*)(cw0 + cs);
        short8 b1 = *(const short8*)(cw1 + cs);
        p0 = __builtin_amdgcn_mfma_f32_16x16x32_bf16(af, b0, p0, 0, 0, 0);
        p1 = __builtin_amdgcn_mfma_f32_16x16x32_bf16(af, b1, p1, 0, 0, 0);
      }
    } else if (wrole == 2 && l < 32) {
      Sx2[l] = Sx2w[l] + Sx2w[32 + l] + Sx2w[64 + l] + Sx2w[96 + l];
    }
    __syncthreads();  // Sx2 ready

    // ---- softmax per n (waves wrole 0,1): k spread over l15 lanes
    if (wrole < 2) {
      float a0[4], a1[4];
#pragma unroll
      for (int r = 0; r < 4; ++r) {
        const float xx = Sx2[wrole * 16 + 4 * q + r];
        float l0 = sc0 * (xx - 2.f * p0[r] + cc0);
        float l1 = sc1 * (xx - 2.f * p1[r] + cc1);
        float m = fmaxf(l0, l1);
        m = fmaxf(m, __shfl_xor(m, 1));
        m = fmaxf(m, __shfl_xor(m, 2));
        m = fmaxf(m, __shfl_xor(m, 4));
        m = fmaxf(m, __shfl_xor(m, 8));
        float e0 = __expf(l0 - m), e1 = __expf(l1 - m);
        float s = e0 + e1;
        s += __shfl_xor(s, 1);
        s += __shfl_xor(s, 2);
        s += __shfl_xor(s, 4);
        s += __shfl_xor(s, 8);
        float inv = 1.0f / s;
        a0[r] = e0 * inv;
        a1[r] = e1 * inv;
      }
      s0acc += a0[0] + a0[1] + a0[2] + a0[3];
      s1acc += a1[0] + a1[1] + a1[2] + a1[3];
      unsigned p00 = (unsigned)f2bf(a0[0]) | ((unsigned)f2bf(a0[1]) << 16);
      unsigned p01 = (unsigned)f2bf(a0[2]) | ((unsigned)f2bf(a0[3]) << 16);
      unsigned p10 = (unsigned)f2bf(a1[0]) | ((unsigned)f2bf(a1[1]) << 16);
      unsigned p11 = (unsigned)f2bf(a1[2]) | ((unsigned)f2bf(a1[3]) << 16);
      const int nc = wrole * 16 + 4 * q;
      *(uint2*)&As[l15 * XP2 + nc] = make_uint2(p00, p01);
      *(uint2*)&As[(16 + l15) * XP2 + nc] = make_uint2(p10, p11);
    }
    __syncthreads();  // As ready

    // ---- phase 2 (all waves): out_tile[k][c] += A . x^T over 32 n
    {
      const int nb = q * 8;
      const short4v* Ap0 = (const short4v*)&As[l15 * XP2 + nb];
      const short4v* Ap1 = (const short4v*)&As[(16 + l15) * XP2 + nb];
      short8 am0 = cat8(Ap0[0], Ap0[1]);
      short8 am1 = cat8(Ap1[0], Ap1[1]);
#pragma unroll
      for (int ct = 0; ct < 8; ++ct) {
        const int c = w * 128 + ct * 16 + l15;
        const short4v* Bp = (const short4v*)&Xl[c * XP2 + nb];
        short8 bx = cat8(Bp[0], Bp[1]);
        acc[ct][0] = __builtin_amdgcn_mfma_f32_16x16x32_bf16(am0, bx, acc[ct][0], 0, 0, 0);
        acc[ct][1] = __builtin_amdgcn_mfma_f32_16x16x32_bf16(am1, bx, acc[ct][1], 0, 0, 0);
      }
    }
    __syncthreads();  // protect Xl/Xn/As before next sub's staging
  }

  // ---- epilogue: streaming partial tile [32 k][512 c] for this block
  float* pout = partials + (size_t)blockIdx.x * KK * CC;
#pragma unroll
  for (int ct = 0; ct < 8; ++ct) {
    const int c = w * 128 + ct * 16 + l15;
#pragma unroll
    for (int m = 0; m < 2; ++m)
#pragma unroll
      for (int r = 0; r < 4; ++r) {
        int k = 16 * m + 4 * q + r;
        pout[k * CC + c] = acc[ct][m][r];
      }
  }
  // asum: only the phase-1 waves hold A-sums; reduce over q lanes
  s0acc += __shfl_xor(s0acc, 16);
  s0acc += __shfl_xor(s0acc, 32);
  s1acc += __shfl_xor(s1acc, 16);
  s1acc += __shfl_xor(s1acc, 32);
  if (wrole < 2 && q == 0) {
    atomicAdd(&asum[b * KK + l15], s0acc);
    atomicAdd(&asum[b * KK + 16 + l15], s1acc);
  }
}

// ---------------- K2: out = sum_chunk partials - asum * cw ----------------
template <int LOG2CH>
__global__ __launch_bounds__(256) void reduce_kernel(
    const float* __restrict__ partials, const float* __restrict__ asum,
    const float* __restrict__ cw, float* __restrict__ out) {
  constexpr int P = 1 << LOG2CH;
  int idx = blockIdx.x * 256 + threadIdx.x;  // float4 index, 65536 total
  int b = idx >> 12;
  int k = (idx >> 7) & 31;
  int c4 = idx & 127;

  float4v o = {0.f, 0.f, 0.f, 0.f};
  const float4v* pb =
      (const float4v*)partials + (((size_t)b << LOG2CH) * KK + k) * 128 + c4;
#pragma unroll 8
  for (int p = 0; p < P; ++p) {
    float4v v = pb[(size_t)p * KK * 128];
    o.x += v.x;
    o.y += v.y;
    o.z += v.z;
    o.w += v.w;
  }
  float4v wv = ((const float4v*)cw)[k * 128 + c4];
  float a = asum[b * KK + k];
  o.x -= a * wv.x;
  o.y -= a * wv.y;
  o.z -= a * wv.z;
  o.w -= a * wv.w;
  ((float4v*)out)[idx] = o;
}

extern "C" void kernel_launch(void* const* d_in, const int* in_sizes, int n_in,
                              void* d_out, int out_size, void* d_ws, size_t ws_size,
                              hipStream_t stream) {
  const float* x = (const float*)d_in[0];      // (16,512,64,64)
  const float* cw = (const float*)d_in[1];     // (32,512)
  const float* scale = (const float*)d_in[2];  // (32,)
  float* out = (float*)d_out;                  // (16,32,512)
  char* ws = (char*)d_ws;

  float* c2 = (float*)ws;                             // 128 B
  unsigned short* cwB = (unsigned short*)(ws + 128);  // 32 KB, plain bf16
  float* asum = (float*)(ws + 32896);                 // 2 KB
  float* partials = (float*)(ws + 35072);             // 32 or 64 MB

  prep_kernel<<<64, 256, 0, stream>>>(cw, cwB, c2, asum);

  const size_t need1024 = 35072 + (size_t)1024 * KK * CC * sizeof(float);
  if (ws_size >= need1024) {
    fused_kernel<6><<<1024, 256, 0, stream>>>(x, cwB, c2, scale, partials, asum);
    reduce_kernel<6><<<256, 256, 0, stream>>>(partials, asum, cw, out);
  } else {
    fused_kernel<5><<<512, 256, 0, stream>>>(x, cwB, c2, scale, partials, asum);
    reduce_kernel<5><<<256, 256, 0, stream>>>(partials, asum, cw, out);
  }
}